// Round 1
// baseline (420.023 us; speedup 1.0000x reference)
//
#include <hip/hip_runtime.h>
#include <math.h>

// MoE gate: logits = x[16384,2048] @ W^T[2048,64]; top-8; softmax over top-8.
//
// Round-3 structure (fixes round-2's uncoalesced 8KB-strided per-lane x reads,
// which made the kernel L1-transaction/latency-bound at VALUBusy 41%):
//   grid  = 256 blocks (64 tokens each), block = 1024 thr = 16 waves.
//   wave  = (expert-group eg in [0,4)) x (K-quarter kh in [0,4))
//           -> acc[16] per lane (lane = token), 512-deep K slice.
//   Per iteration: ALL threads cooperatively stage x[4][64 tok][64 floats]
//   (64 KB LDS, XOR-swizzled rows: byte ^= (row&7)<<4) with coalesced float4
//   loads, register-prefetched one iteration ahead; compute reads x from LDS
//   (8-dwords/bank uniform floor), W via wave-uniform scalar loads.
//   K-quarter partials reduced by overlaying part[kh][e][t] into the staging
//   buffer after the last compute barrier (no atomics, no zero-init).
//   Wave 0: per-lane top-8 (strict >, matches lax.top_k ties) + softmax.

#define H_DIM 2048
#define N_EXP 64
#define TOPK 8
#define TOK 64                // tokens per block
#define NKH 4                 // K quarters (one per wave row)
#define KH 512                // H_DIM / NKH
#define CH 64                 // floats per token per quarter per iteration
#define NIT 8                 // KH / CH
#define E_PER_WAVE 16
#define QBYTES (TOK * CH * 4) // 16384 B per quarter region

__global__ __launch_bounds__(1024, 4) void moe_gate_kernel(
    const float* __restrict__ x, const float* __restrict__ w,
    float* __restrict__ out, int n_tokens) {
  // 64 KB. Main loop: xs[quarter][row][64] floats, rows XOR-swizzled.
  // Epilogue: reused as part[kh][expert][token] (4*64*64 floats exactly).
  __shared__ float xs[NKH * TOK * CH];
  char* const xb = (char*)xs;

  const int tid = threadIdx.x;
  const int lane = tid & 63;
  const int wave = tid >> 6;
  const int t0 = blockIdx.x * TOK;

  // staging coords: 16 threads per token row, float4 granularity
  const int srow = tid >> 4;   // token row 0..63
  const int scol4 = tid & 15;  // float4 column within 64-float chunk
  const int soff = srow * 256 + (((scol4 << 4) ^ ((srow & 7) << 4)));

  // wave-uniform roles, forced into SGPRs
  const int eg = __builtin_amdgcn_readfirstlane(wave & 3);
  const int kh = __builtin_amdgcn_readfirstlane(wave >> 2);
  const int e0 = eg * E_PER_WAVE;

  const float* gbase = x + (size_t)(t0 + srow) * H_DIM + scol4 * 4;

  float acc[E_PER_WAVE];
#pragma unroll
  for (int e = 0; e < E_PER_WAVE; ++e) acc[e] = 0.f;

  // prefetch iteration 0 (4 float4 per thread, coalesced)
  float4 pre[NKH];
#pragma unroll
  for (int j = 0; j < NKH; ++j)
    pre[j] = *(const float4*)(gbase + j * KH);

  const int lswz = (lane & 7) << 4;
  const int lbase = kh * QBYTES + lane * 256;

  for (int i = 0; i < NIT; ++i) {
    __syncthreads();  // previous compute done -> xs writable
#pragma unroll
    for (int j = 0; j < NKH; ++j)
      *(float4*)(xb + j * QBYTES + soff) = pre[j];
    __syncthreads();  // tile ready
    if (i + 1 < NIT) {
      // issue next tile's loads now; latency hides under the FMA phase
#pragma unroll
      for (int j = 0; j < NKH; ++j)
        pre[j] = *(const float4*)(gbase + j * KH + (i + 1) * CH);
    }
#pragma unroll
    for (int cc = 0; cc < 4; ++cc) {
      float xv[16];
#pragma unroll
      for (int q = 0; q < 4; ++q) {
        float4 v = *(const float4*)(
            xb + lbase + ((((cc * 4 + q) << 4) ^ lswz)));
        xv[q * 4 + 0] = v.x;
        xv[q * 4 + 1] = v.y;
        xv[q * 4 + 2] = v.z;
        xv[q * 4 + 3] = v.w;
      }
#pragma unroll
      for (int e = 0; e < E_PER_WAVE; ++e) {
        // uniform address (e0, kh wave-uniform; i, cc loop) -> scalar loads
        const float* wr =
            w + (size_t)(e0 + e) * H_DIM + kh * KH + i * CH + cc * 16;
#pragma unroll
        for (int j = 0; j < 16; ++j) acc[e] = fmaf(xv[j], wr[j], acc[e]);
      }
    }
  }

  // reduce K-quarter partials: overlay part[kh][e][t] into the staging buffer
  __syncthreads();  // all xs reads done
#pragma unroll
  for (int e = 0; e < E_PER_WAVE; ++e)
    xs[kh * (N_EXP * TOK) + (e0 + e) * TOK + lane] = acc[e];
  __syncthreads();

  if (wave != 0) return;

  // ---- wave 0: per-lane top-8 over 64 logits (lane = token) ----
  float lg[N_EXP];
#pragma unroll
  for (int e = 0; e < N_EXP; ++e)
    lg[e] = (xs[e * TOK + lane] + xs[1 * (N_EXP * TOK) + e * TOK + lane]) +
            (xs[2 * (N_EXP * TOK) + e * TOK + lane] +
             xs[3 * (N_EXP * TOK) + e * TOK + lane]);

  float bw[TOPK];
  int bi[TOPK];
#pragma unroll
  for (int k = 0; k < TOPK; ++k) {
    float m = lg[0];
    int mi = 0;
#pragma unroll
    for (int e = 1; e < N_EXP; ++e) {
      if (lg[e] > m) {  // strict > keeps lowest index on tie (lax.top_k)
        m = lg[e];
        mi = e;
      }
    }
    bw[k] = m;
    bi[k] = mi;
#pragma unroll
    for (int e = 0; e < N_EXP; ++e)
      if (e == mi) lg[e] = -INFINITY;
  }

  // softmax over top-8 == full softmax renormalized to top-8 (exact)
  const float mx = bw[0];
  float ew[TOPK];
  float s = 0.f;
#pragma unroll
  for (int k = 0; k < TOPK; ++k) {
    ew[k] = expf(bw[k] - mx);
    s += ew[k];
  }
  const float inv = 1.f / s;

  float4 w0, w1, i0, i1;
  w0.x = ew[0] * inv; w0.y = ew[1] * inv; w0.z = ew[2] * inv; w0.w = ew[3] * inv;
  w1.x = ew[4] * inv; w1.y = ew[5] * inv; w1.z = ew[6] * inv; w1.w = ew[7] * inv;
  i0.x = (float)bi[0]; i0.y = (float)bi[1]; i0.z = (float)bi[2]; i0.w = (float)bi[3];
  i1.x = (float)bi[4]; i1.y = (float)bi[5]; i1.z = (float)bi[6]; i1.w = (float)bi[7];

  const int t = t0 + lane;
  float4* ow = reinterpret_cast<float4*>(out + (size_t)t * TOPK);
  ow[0] = w0;
  ow[1] = w1;
  float4* oi =
      reinterpret_cast<float4*>(out + (size_t)n_tokens * TOPK + (size_t)t * TOPK);
  oi[0] = i0;
  oi[1] = i1;
}

extern "C" void kernel_launch(void* const* d_in, const int* in_sizes, int n_in,
                              void* d_out, int out_size, void* d_ws,
                              size_t ws_size, hipStream_t stream) {
  const float* x = (const float*)d_in[0];
  const float* w = (const float*)d_in[1];
  float* out = (float*)d_out;
  const int n_tokens = in_sizes[0] / H_DIM;    // 16384
  const int n_blocks = n_tokens / TOK;         // 256
  moe_gate_kernel<<<n_blocks, 1024, 0, stream>>>(x, w, out, n_tokens);
}